// Round 7
// baseline (182.207 us; speedup 1.0000x reference)
//
#include <hip/hip_runtime.h>

#define BB 8
#define CC 128

// ---------------- fused inLay: global->combine->LDS(stride 68) + sample + box mask ----
__global__ __launch_bounds__(256) void inlay_sample_kernel(
    const float* __restrict__ x, const float* __restrict__ lin,
    const float* __restrict__ geo, const float* __restrict__ box,
    float* __restrict__ out) {
  const int H = 64, W = 64, HW = 4096;
  __shared__ __align__(16) float cp[64 * 68];   // 17.4 KB combined plane
  int bc = blockIdx.x;
  int c = bc & (CC - 1);
  int b = bc >> 7;
  int tid = threadIdx.x;
  const float* xb = x + (size_t)b * 3 * HW;

  float w0 = lin[c * 3 + 0], w1 = lin[c * 3 + 1], w2 = lin[c * 3 + 2];

#pragma unroll
  for (int k = 0; k < 4; ++k) {
    int i4 = tid + k * 256;
    int base = i4 * 4;
    float4 f0 = *reinterpret_cast<const float4*>(&xb[base]);
    float4 f1 = *reinterpret_cast<const float4*>(&xb[HW + base]);
    float4 f2 = *reinterpret_cast<const float4*>(&xb[2 * HW + base]);
    float4 cv;
    cv.x = w0 * f0.x + w1 * f1.x + w2 * f2.x;
    cv.y = w0 * f0.y + w1 * f1.y + w2 * f2.y;
    cv.z = w0 * f0.z + w1 * f1.z + w2 * f2.z;
    cv.w = w0 * f0.w + w1 * f1.w + w2 * f2.w;
    int h = i4 >> 4, w = (i4 & 15) * 4;
    *reinterpret_cast<float4*>(&cp[h * 68 + w]) = cv;
  }
  __syncthreads();

  const float* g = geo + c * 6;
  const float* bx = box + c * 6;
  float g0 = g[0], g1 = g[1], g2 = g[2], g3 = g[3], g4 = g[4], g5 = g[5];
  float b0 = bx[0], b1 = bx[1], b2 = bx[2], b3 = bx[3], b4 = bx[4], b5 = bx[5];
  float* o = out + ((size_t)b * CC + c) * HW;

#pragma unroll
  for (int k = 0; k < 16; ++k) {
    int px = tid + k * 256;
    int h = px >> 6, w = px & 63;
    float xs = (2.0f * w + 1.0f) / W - 1.0f;
    float ys = (2.0f * h + 1.0f) / H - 1.0f;
    float gx = g0 * xs + g1 * ys + g2;
    float gy = g3 * xs + g4 * ys + g5;
    float ix = ((gx + 1.0f) * W - 1.0f) * 0.5f;
    float iy = ((gy + 1.0f) * H - 1.0f) * 0.5f;
    float x0 = floorf(ix), y0 = floorf(iy);
    float wx = ix - x0, wy = iy - y0;
    float v[2][2];
#pragma unroll
    for (int dy = 0; dy < 2; ++dy)
#pragma unroll
      for (int dx = 0; dx < 2; ++dx) {
        float xf = x0 + dx, yf = y0 + dy;
        bool valid = (xf >= 0.0f) && (xf <= 63.0f) && (yf >= 0.0f) && (yf <= 63.0f);
        int xi = (int)fminf(fmaxf(xf, 0.0f), 63.0f);
        int yi = (int)fminf(fmaxf(yf, 0.0f), 63.0f);
        v[dy][dx] = valid ? cp[yi * 68 + xi] : 0.0f;
      }
    float samp = (1.0f - wy) * ((1.0f - wx) * v[0][0] + wx * v[0][1]) +
                 wy * ((1.0f - wx) * v[1][0] + wx * v[1][1]);

    float bgx = b0 * xs + b1 * ys + b2;
    float bgy = b3 * xs + b4 * ys + b5;
    float bix = ((bgx + 1.0f) * W - 1.0f) * 0.5f;
    float biy = ((bgy + 1.0f) * H - 1.0f) * 0.5f;
    float bx0 = floorf(bix), by0 = floorf(biy);
    float bwx = bix - bx0, bwy = biy - by0;
    float m[2][2];
#pragma unroll
    for (int dy = 0; dy < 2; ++dy)
#pragma unroll
      for (int dx = 0; dx < 2; ++dx) {
        float xf = bx0 + dx, yf = by0 + dy;
        m[dy][dx] = ((xf >= 0.0f) && (xf <= 63.0f) && (yf >= 0.0f) && (yf <= 63.0f)) ? 1.0f : 0.0f;
      }
    float mask = (1.0f - bwy) * ((1.0f - bwx) * m[0][0] + bwx * m[0][1]) +
                 bwy * ((1.0f - bwx) * m[1][0] + bwx * m[1][1]);
    o[px] = samp * mask;
  }
}

// ---------------- fused layer-0: GEMM (4 ch/block, k-ascending == tiled order) ------
// + sample(64x64) + MaxPool2d_G -> 32x32. One block per (batch, 4-ch group).
// XCD swizzle: b = blockIdx & 7 -> all 32 blocks of a batch share one XCD's L2.
__global__ __launch_bounds__(1024, 4) void fused_gs_kernel(
    const float* __restrict__ lin, const float* __restrict__ x,
    const float* __restrict__ geo, const float* __restrict__ box,
    float* __restrict__ out) {
  __shared__ __align__(16) float planes[4][64 * 68];   // 69.6 KB GEMM output
  __shared__ __align__(16) float sp[64 * 68];          // 17.4 KB sampled plane
  __shared__ __align__(16) float cb[64 * 100];         // 25.6 KB column-band sums
  __shared__ float wv[16];
  __shared__ int wi[16];
  __shared__ int am_s;

  int b = blockIdx.x & 7;
  int c0 = (blockIdx.x >> 3) * 4;
  int tid = threadIdx.x;
  const float* xb = x + (size_t)b * 128 * 4096;
  const float* l0 = lin + (c0 + 0) * 128;
  const float* l1 = lin + (c0 + 1) * 128;
  const float* l2 = lin + (c0 + 2) * 128;
  const float* l3 = lin + (c0 + 3) * 128;
  int px4 = tid * 4;
  int ph = tid >> 4, pw4 = (tid & 15) * 4;   // (h, w4) of this px group

  // ---- GEMM: acc[c] over k ascending (bit-identical to tiled gemm64) ----
  float4 a0 = make_float4(0.f, 0.f, 0.f, 0.f);
  float4 a1 = a0, a2 = a0, a3 = a0;
#pragma unroll 8
  for (int k = 0; k < 128; ++k) {
    float4 xv = *reinterpret_cast<const float4*>(&xb[(size_t)k * 4096 + px4]);
    float s0 = l0[k], s1 = l1[k], s2 = l2[k], s3 = l3[k];   // block-uniform -> s_load
    a0.x += s0 * xv.x; a0.y += s0 * xv.y; a0.z += s0 * xv.z; a0.w += s0 * xv.w;
    a1.x += s1 * xv.x; a1.y += s1 * xv.y; a1.z += s1 * xv.z; a1.w += s1 * xv.w;
    a2.x += s2 * xv.x; a2.y += s2 * xv.y; a2.z += s2 * xv.z; a2.w += s2 * xv.w;
    a3.x += s3 * xv.x; a3.y += s3 * xv.y; a3.z += s3 * xv.z; a3.w += s3 * xv.w;
  }
  *reinterpret_cast<float4*>(&planes[0][ph * 68 + pw4]) = a0;
  *reinterpret_cast<float4*>(&planes[1][ph * 68 + pw4]) = a1;
  *reinterpret_cast<float4*>(&planes[2][ph * 68 + pw4]) = a2;
  *reinterpret_cast<float4*>(&planes[3][ph * 68 + pw4]) = a3;
  __syncthreads();

  // ---- per-channel sample + maxpool (round-6-validated phases) ----
  for (int c = 0; c < 4; ++c) {
    const float* g = geo + (c0 + c) * 6;
    const float* bx = box + (c0 + c) * 6;
    float g0 = g[0], g1 = g[1], g2 = g[2], g3 = g[3], g4 = g[4], g5 = g[5];
    float b0 = bx[0], b1 = bx[1], b2 = bx[2], b3 = bx[3], b4 = bx[4], b5 = bx[5];
    const float* pl = planes[c];

    // phase 2: sample 4 px/thread -> sp
#pragma unroll
    for (int kk = 0; kk < 4; ++kk) {
      int px = tid + kk * 1024;
      int h = px >> 6, w = px & 63;
      float xs = (2.0f * w + 1.0f) / 64.0f - 1.0f;
      float ys = (2.0f * h + 1.0f) / 64.0f - 1.0f;
      float gx = g0 * xs + g1 * ys + g2;
      float gy = g3 * xs + g4 * ys + g5;
      float ix = ((gx + 1.0f) * 64.0f - 1.0f) * 0.5f;
      float iy = ((gy + 1.0f) * 64.0f - 1.0f) * 0.5f;
      float x0 = floorf(ix), y0 = floorf(iy);
      float wx = ix - x0, wy = iy - y0;
      float v[2][2];
#pragma unroll
      for (int dy = 0; dy < 2; ++dy)
#pragma unroll
        for (int dx = 0; dx < 2; ++dx) {
          float xf = x0 + dx, yf = y0 + dy;
          bool valid = (xf >= 0.0f) && (xf <= 63.0f) && (yf >= 0.0f) && (yf <= 63.0f);
          int xi = (int)fminf(fmaxf(xf, 0.0f), 63.0f);
          int yi = (int)fminf(fmaxf(yf, 0.0f), 63.0f);
          v[dy][dx] = valid ? pl[yi * 68 + xi] : 0.0f;
        }
      float samp = (1.0f - wy) * ((1.0f - wx) * v[0][0] + wx * v[0][1]) +
                   wy * ((1.0f - wx) * v[1][0] + wx * v[1][1]);
      float bgx = b0 * xs + b1 * ys + b2;
      float bgy = b3 * xs + b4 * ys + b5;
      float bix = ((bgx + 1.0f) * 64.0f - 1.0f) * 0.5f;
      float biy = ((bgy + 1.0f) * 64.0f - 1.0f) * 0.5f;
      float bx0 = floorf(bix), by0 = floorf(biy);
      float bwx = bix - bx0, bwy = biy - by0;
      float m[2][2];
#pragma unroll
      for (int dy = 0; dy < 2; ++dy)
#pragma unroll
        for (int dx = 0; dx < 2; ++dx) {
          float xf = bx0 + dx, yf = by0 + dy;
          m[dy][dx] = ((xf >= 0.0f) && (xf <= 63.0f) && (yf >= 0.0f) && (yf <= 63.0f)) ? 1.0f : 0.0f;
        }
      float mask = (1.0f - bwy) * ((1.0f - bwx) * m[0][0] + bwx * m[0][1]) +
                   bwy * ((1.0f - bwx) * m[1][0] + bwx * m[1][1]);
      sp[h * 68 + w] = samp * mask;
    }
    __syncthreads();

    // phase 3: column band sums (4-row strips, threads 0..255; pads zeroed by 256..767)
    if (tid < 256) {
      int strip = tid >> 4, w4 = (tid & 15) * 4;
      int h0 = strip * 4;
      float4 s0v = make_float4(0.f, 0.f, 0.f, 0.f), s1v = s0v, s2v = s0v, s3v = s0v;
#pragma unroll
      for (int j = 0; j < 35; ++j) {
        int r = h0 + j - 16;
        bool valid = (r >= 0) && (r < 64);
        int rc = valid ? r : 0;
        float4 f = *reinterpret_cast<const float4*>(&sp[rc * 68 + w4]);
        f.x = valid ? f.x : 0.0f; f.y = valid ? f.y : 0.0f;
        f.z = valid ? f.z : 0.0f; f.w = valid ? f.w : 0.0f;
        if (j <= 31) { s0v.x += f.x; s0v.y += f.y; s0v.z += f.z; s0v.w += f.w; }
        if (j >= 1 && j <= 32) { s1v.x += f.x; s1v.y += f.y; s1v.z += f.z; s1v.w += f.w; }
        if (j >= 2 && j <= 33) { s2v.x += f.x; s2v.y += f.y; s2v.z += f.z; s2v.w += f.w; }
        if (j >= 3) { s3v.x += f.x; s3v.y += f.y; s3v.z += f.z; s3v.w += f.w; }
      }
      *reinterpret_cast<float4*>(&cb[(h0 + 0) * 100 + 16 + w4]) = s0v;
      *reinterpret_cast<float4*>(&cb[(h0 + 1) * 100 + 16 + w4]) = s1v;
      *reinterpret_cast<float4*>(&cb[(h0 + 2) * 100 + 16 + w4]) = s2v;
      *reinterpret_cast<float4*>(&cb[(h0 + 3) * 100 + 16 + w4]) = s3v;
    } else if (tid < 768) {
      int l = tid - 256;
      int row = l >> 3, gq = l & 7;
      int base = row * 100 + ((gq < 4) ? gq * 4 : 80 + (gq - 4) * 4);
      *reinterpret_cast<float4*>(&cb[base]) = make_float4(0.f, 0.f, 0.f, 0.f);
    }
    __syncthreads();

    // phase 4: row window sums + argmax
    float best = -3.402823466e+38f;
    int bidx = 0x7fffffff;
    {
      int h = tid >> 4, w4 = (tid & 15) * 4;
      float s0 = 0.f, s1 = 0.f, s2 = 0.f, s3 = 0.f;
#pragma unroll
      for (int q = 0; q < 9; ++q) {
        float4 f = *reinterpret_cast<const float4*>(&cb[h * 100 + w4 + 4 * q]);
        float fe[4] = {f.x, f.y, f.z, f.w};
#pragma unroll
        for (int e = 0; e < 4; ++e) {
          int u = 4 * q + e;
          if (u <= 31) s0 += fe[e];
          if (u >= 1 && u <= 32) s1 += fe[e];
          if (u >= 2 && u <= 33) s2 += fe[e];
          if (u >= 3 && u <= 34) s3 += fe[e];
        }
      }
      float sv[4] = {s0, s1, s2, s3};
#pragma unroll
      for (int d = 0; d < 4; ++d) {
        int i = (h << 6) + w4 + d;
        if (sv[d] > best) { best = sv[d]; bidx = i; }
      }
    }
#pragma unroll
    for (int off = 32; off > 0; off >>= 1) {
      float v2 = __shfl_down(best, off);
      int i2 = __shfl_down(bidx, off);
      if (v2 > best || (v2 == best && i2 < bidx)) { best = v2; bidx = i2; }
    }
    if ((tid & 63) == 0) { wv[tid >> 6] = best; wi[tid >> 6] = bidx; }
    __syncthreads();
    if (tid == 0) {
      float bv = wv[0]; int bi = wi[0];
#pragma unroll
      for (int k = 1; k < 16; ++k)
        if (wv[k] > bv || (wv[k] == bv && wi[k] < bi)) { bv = wv[k]; bi = wi[k]; }
      am_s = bi;
    }
    __syncthreads();

    // phase 5: 32x32 windowed gather
    int am = am_s;
    int r = am >> 6, cx = am & 63;
    float* o = out + ((size_t)b * CC + c0 + c) * 1024;
    {
      int oi = tid >> 5, oj = tid & 31;
      int rr = r + oi - 16, cj = cx + oj - 16;
      bool v = (rr >= 0) && (rr < 64) && (cj >= 0) && (cj < 64);
      int rrc = v ? rr : 0, cjc = v ? cj : 0;
      o[tid] = v ? sp[rrc * 68 + cjc] : 0.0f;
    }
    __syncthreads();   // sp/cb reused next channel
  }
}

// ---------------- fused 32x32 layer: GEMM (4 ch/block) + sample + optional pool ----
template <bool POOL>
__global__ __launch_bounds__(256) void fused32_kernel(
    const float* __restrict__ lin, const float* __restrict__ x,
    const float* __restrict__ geo, const float* __restrict__ box,
    float* __restrict__ out, float* __restrict__ pooled) {
  const int H = 32, W = 32, HW = 1024;
  __shared__ __align__(16) float pls[4][1024];
  __shared__ float wred[16];
  int b = blockIdx.x & 7;                 // XCD swizzle: batch per XCD
  int c0 = (blockIdx.x >> 3) * 4;
  int tid = threadIdx.x;
  const float* xb = x + (size_t)b * 128 * HW;
  const float* l0 = lin + (c0 + 0) * 128;
  const float* l1 = lin + (c0 + 1) * 128;
  const float* l2 = lin + (c0 + 2) * 128;
  const float* l3 = lin + (c0 + 3) * 128;
  int px4 = tid * 4;

  float4 acc0 = make_float4(0.f, 0.f, 0.f, 0.f);
  float4 acc1 = acc0, acc2 = acc0, acc3 = acc0;
#pragma unroll 8
  for (int k = 0; k < 128; ++k) {
    float4 xv = *reinterpret_cast<const float4*>(&xb[(size_t)k * HW + px4]);
    float s0 = l0[k], s1 = l1[k], s2 = l2[k], s3 = l3[k];
    acc0.x += s0 * xv.x; acc0.y += s0 * xv.y; acc0.z += s0 * xv.z; acc0.w += s0 * xv.w;
    acc1.x += s1 * xv.x; acc1.y += s1 * xv.y; acc1.z += s1 * xv.z; acc1.w += s1 * xv.w;
    acc2.x += s2 * xv.x; acc2.y += s2 * xv.y; acc2.z += s2 * xv.z; acc2.w += s2 * xv.w;
    acc3.x += s3 * xv.x; acc3.y += s3 * xv.y; acc3.z += s3 * xv.z; acc3.w += s3 * xv.w;
  }
  *reinterpret_cast<float4*>(&pls[0][px4]) = acc0;
  *reinterpret_cast<float4*>(&pls[1][px4]) = acc1;
  *reinterpret_cast<float4*>(&pls[2][px4]) = acc2;
  *reinterpret_cast<float4*>(&pls[3][px4]) = acc3;
  __syncthreads();

  float psum[4] = {0.f, 0.f, 0.f, 0.f};
#pragma unroll
  for (int c = 0; c < 4; ++c) {
    const float* g = geo + (c0 + c) * 6;
    const float* bxp = box + (c0 + c) * 6;
    float g0 = g[0], g1 = g[1], g2 = g[2], g3 = g[3], g4 = g[4], g5 = g[5];
    float b0 = bxp[0], b1 = bxp[1], b2 = bxp[2], b3 = bxp[3], b4 = bxp[4], b5 = bxp[5];
    float* o = out + ((size_t)b * CC + c0 + c) * HW;
    const float* pl = pls[c];
#pragma unroll
    for (int k = 0; k < 4; ++k) {
      int px = tid + k * 256;
      int h = px >> 5, w = px & 31;
      float xs = (2.0f * w + 1.0f) / W - 1.0f;
      float ys = (2.0f * h + 1.0f) / H - 1.0f;
      float gx = g0 * xs + g1 * ys + g2;
      float gy = g3 * xs + g4 * ys + g5;
      float ix = ((gx + 1.0f) * W - 1.0f) * 0.5f;
      float iy = ((gy + 1.0f) * H - 1.0f) * 0.5f;
      float x0 = floorf(ix), y0 = floorf(iy);
      float wx = ix - x0, wy = iy - y0;
      float v[2][2];
#pragma unroll
      for (int dy = 0; dy < 2; ++dy)
#pragma unroll
        for (int dx = 0; dx < 2; ++dx) {
          float xf = x0 + dx, yf = y0 + dy;
          bool valid = (xf >= 0.0f) && (xf <= 31.0f) && (yf >= 0.0f) && (yf <= 31.0f);
          int xi = (int)fminf(fmaxf(xf, 0.0f), 31.0f);
          int yi = (int)fminf(fmaxf(yf, 0.0f), 31.0f);
          v[dy][dx] = valid ? pl[yi * 32 + xi] : 0.0f;
        }
      float samp = (1.0f - wy) * ((1.0f - wx) * v[0][0] + wx * v[0][1]) +
                   wy * ((1.0f - wx) * v[1][0] + wx * v[1][1]);
      float bgx = b0 * xs + b1 * ys + b2;
      float bgy = b3 * xs + b4 * ys + b5;
      float bix = ((bgx + 1.0f) * W - 1.0f) * 0.5f;
      float biy = ((bgy + 1.0f) * H - 1.0f) * 0.5f;
      float bx0 = floorf(bix), by0 = floorf(biy);
      float bwx = bix - bx0, bwy = biy - by0;
      float m[2][2];
#pragma unroll
      for (int dy = 0; dy < 2; ++dy)
#pragma unroll
        for (int dx = 0; dx < 2; ++dx) {
          float xf = bx0 + dx, yf = by0 + dy;
          m[dy][dx] = ((xf >= 0.0f) && (xf <= 31.0f) && (yf >= 0.0f) && (yf <= 31.0f)) ? 1.0f : 0.0f;
        }
      float mask = (1.0f - bwy) * ((1.0f - bwx) * m[0][0] + bwx * m[0][1]) +
                   bwy * ((1.0f - bwx) * m[1][0] + bwx * m[1][1]);
      float res = samp * mask;
      o[px] = res;
      if (POOL) psum[c] += res;
    }
  }
  if (POOL) {
    int lane = tid & 63, wid = tid >> 6;
#pragma unroll
    for (int c = 0; c < 4; ++c) {
      float r = psum[c];
#pragma unroll
      for (int off = 32; off > 0; off >>= 1) r += __shfl_down(r, off);
      if (lane == 0) wred[c * 4 + wid] = r;
    }
    __syncthreads();
    if (tid < 4) {
      float t = wred[tid * 4] + wred[tid * 4 + 1] + wred[tid * 4 + 2] + wred[tid * 4 + 3];
      pooled[b * CC + c0 + tid] = t * (1.0f / 1024.0f);
    }
  }
}

// ---------------- dense head ----------------
__global__ __launch_bounds__(128) void dense_kernel(
    const float* __restrict__ pooled, const float* __restrict__ w,
    const float* __restrict__ bias, float* __restrict__ out) {
  int t = threadIdx.x;
  if (t < 80) {
    int b = t / 10, o = t % 10;
    float s = bias[o];
    const float* pb = pooled + b * 128;
    const float* wo = w + o * 128;
    for (int c = 0; c < 128; ++c) s += pb[c] * wo[c];
    out[b * 10 + o] = s;
  }
}

extern "C" void kernel_launch(void* const* d_in, const int* in_sizes, int n_in,
                              void* d_out, int out_size, void* d_ws, size_t ws_size,
                              hipStream_t stream) {
  const float* x     = (const float*)d_in[0];   // [8,3,64,64]
  const float* geo0  = (const float*)d_in[1];   // [128,2,3]
  const float* lin0  = (const float*)d_in[2];   // [128,3]
  const float* box0  = (const float*)d_in[3];   // [128,2,3]
  const float* geos  = (const float*)d_in[4];   // [3,128,2,3]
  const float* lins  = (const float*)d_in[5];   // [3,128,128]
  const float* boxes = (const float*)d_in[6];   // [3,128,2,3]
  const float* dw    = (const float*)d_in[7];   // [10,128]
  const float* db    = (const float*)d_in[8];   // [10]

  float* out  = (float*)d_out;      // [8,10] then feat [8,128,32,32]
  float* feat = out + 80;
  float* ws   = (float*)d_ws;
  float* ws0  = ws;                 // 16 MB
  float* ws1  = ws + 4194304;       // 16 MB
  float* pooled = ws + 8388608;     // 1024 floats

  // inLay: fused combine(Ci=3) + sample -> ws1
  inlay_sample_kernel<<<dim3(BB * CC), 256, 0, stream>>>(x, lin0, geo0, box0, ws1);
  // layer 0+1: fused GEMM + sample + maxpool -> [8,128,32,32] in ws0
  fused_gs_kernel<<<dim3(256), 1024, 0, stream>>>(lins, ws1, geos, boxes, ws0);
  // layer 2: fused GEMM + sample
  fused32_kernel<false><<<dim3(256), 256, 0, stream>>>(lins + 16384, ws0, geos + 768, boxes + 768, ws1, nullptr);
  // layer 3: fused GEMM + sample + mean-pool, feat straight to d_out
  fused32_kernel<true><<<dim3(256), 256, 0, stream>>>(lins + 32768, ws1, geos + 1536, boxes + 1536, feat, pooled);
  // head
  dense_kernel<<<1, 128, 0, stream>>>(pooled, dw, db, out);
}

// Round 8
// 163.321 us; speedup vs baseline: 1.1156x; 1.1156x over previous
//
#include <hip/hip_runtime.h>

#define BB 8
#define CC 128

// ---------------- fused inLay: global->combine->LDS(stride 68) + sample + box mask ----
__global__ __launch_bounds__(256) void inlay_sample_kernel(
    const float* __restrict__ x, const float* __restrict__ lin,
    const float* __restrict__ geo, const float* __restrict__ box,
    float* __restrict__ out) {
  const int H = 64, W = 64, HW = 4096;
  __shared__ __align__(16) float cp[64 * 68];   // 17.4 KB combined plane
  int bc = blockIdx.x;
  int c = bc & (CC - 1);
  int b = bc >> 7;
  int tid = threadIdx.x;
  const float* xb = x + (size_t)b * 3 * HW;

  float w0 = lin[c * 3 + 0], w1 = lin[c * 3 + 1], w2 = lin[c * 3 + 2];

#pragma unroll
  for (int k = 0; k < 4; ++k) {
    int i4 = tid + k * 256;
    int base = i4 * 4;
    float4 f0 = *reinterpret_cast<const float4*>(&xb[base]);
    float4 f1 = *reinterpret_cast<const float4*>(&xb[HW + base]);
    float4 f2 = *reinterpret_cast<const float4*>(&xb[2 * HW + base]);
    float4 cv;
    cv.x = w0 * f0.x + w1 * f1.x + w2 * f2.x;
    cv.y = w0 * f0.y + w1 * f1.y + w2 * f2.y;
    cv.z = w0 * f0.z + w1 * f1.z + w2 * f2.z;
    cv.w = w0 * f0.w + w1 * f1.w + w2 * f2.w;
    int h = i4 >> 4, w = (i4 & 15) * 4;
    *reinterpret_cast<float4*>(&cp[h * 68 + w]) = cv;
  }
  __syncthreads();

  const float* g = geo + c * 6;
  const float* bx = box + c * 6;
  float g0 = g[0], g1 = g[1], g2 = g[2], g3 = g[3], g4 = g[4], g5 = g[5];
  float b0 = bx[0], b1 = bx[1], b2 = bx[2], b3 = bx[3], b4 = bx[4], b5 = bx[5];
  float* o = out + ((size_t)b * CC + c) * HW;

#pragma unroll
  for (int k = 0; k < 16; ++k) {
    int px = tid + k * 256;
    int h = px >> 6, w = px & 63;
    float xs = (2.0f * w + 1.0f) / W - 1.0f;
    float ys = (2.0f * h + 1.0f) / H - 1.0f;
    float gx = g0 * xs + g1 * ys + g2;
    float gy = g3 * xs + g4 * ys + g5;
    float ix = ((gx + 1.0f) * W - 1.0f) * 0.5f;
    float iy = ((gy + 1.0f) * H - 1.0f) * 0.5f;
    float x0 = floorf(ix), y0 = floorf(iy);
    float wx = ix - x0, wy = iy - y0;
    float v[2][2];
#pragma unroll
    for (int dy = 0; dy < 2; ++dy)
#pragma unroll
      for (int dx = 0; dx < 2; ++dx) {
        float xf = x0 + dx, yf = y0 + dy;
        bool valid = (xf >= 0.0f) && (xf <= 63.0f) && (yf >= 0.0f) && (yf <= 63.0f);
        int xi = (int)fminf(fmaxf(xf, 0.0f), 63.0f);
        int yi = (int)fminf(fmaxf(yf, 0.0f), 63.0f);
        v[dy][dx] = valid ? cp[yi * 68 + xi] : 0.0f;
      }
    float samp = (1.0f - wy) * ((1.0f - wx) * v[0][0] + wx * v[0][1]) +
                 wy * ((1.0f - wx) * v[1][0] + wx * v[1][1]);

    float bgx = b0 * xs + b1 * ys + b2;
    float bgy = b3 * xs + b4 * ys + b5;
    float bix = ((bgx + 1.0f) * W - 1.0f) * 0.5f;
    float biy = ((bgy + 1.0f) * H - 1.0f) * 0.5f;
    float bx0 = floorf(bix), by0 = floorf(biy);
    float bwx = bix - bx0, bwy = biy - by0;
    float m[2][2];
#pragma unroll
    for (int dy = 0; dy < 2; ++dy)
#pragma unroll
      for (int dx = 0; dx < 2; ++dx) {
        float xf = bx0 + dx, yf = by0 + dy;
        m[dy][dx] = ((xf >= 0.0f) && (xf <= 63.0f) && (yf >= 0.0f) && (yf <= 63.0f)) ? 1.0f : 0.0f;
      }
    float mask = (1.0f - bwy) * ((1.0f - bwx) * m[0][0] + bwx * m[0][1]) +
                 bwy * ((1.0f - bwx) * m[1][0] + bwx * m[1][1]);
    o[px] = samp * mask;
  }
}

// ---------------- layer-0 GEMM: 64x64 tile, 4x4/thread, register prefetch ----------
__global__ __launch_bounds__(256) void gemm64_kernel(
    const float* __restrict__ lin, const float* __restrict__ x,
    float* __restrict__ y, int HW) {
  const int Ci = 128;
  __shared__ __align__(16) float As[16][68];
  __shared__ __align__(16) float Bs[16][64];
  int b = blockIdx.z;
  const float* xb = x + (size_t)b * Ci * HW;
  float* yb = y + (size_t)b * CC * HW;
  int tid = threadIdx.x;
  int tx = tid & 15, ty = tid >> 4;
  int row0 = blockIdx.y * 64;
  int col0 = blockIdx.x * 64;
  int m = tid >> 2, kq = (tid & 3) * 4;
  int kk = tid >> 4, n4 = (tid & 15) * 4;
  float acc[4][4] = {};
  float4 ra = *reinterpret_cast<const float4*>(&lin[(row0 + m) * Ci + kq]);
  float4 rb = *reinterpret_cast<const float4*>(&xb[(size_t)kk * HW + col0 + n4]);
  for (int k0 = 0; k0 < 128; k0 += 16) {
    __syncthreads();
    As[kq + 0][m] = ra.x; As[kq + 1][m] = ra.y; As[kq + 2][m] = ra.z; As[kq + 3][m] = ra.w;
    *reinterpret_cast<float4*>(&Bs[kk][n4]) = rb;
    __syncthreads();
    if (k0 + 16 < 128) {
      ra = *reinterpret_cast<const float4*>(&lin[(row0 + m) * Ci + k0 + 16 + kq]);
      rb = *reinterpret_cast<const float4*>(&xb[(size_t)(k0 + 16 + kk) * HW + col0 + n4]);
    }
#pragma unroll
    for (int kki = 0; kki < 16; ++kki) {
      float4 a4 = *reinterpret_cast<const float4*>(&As[kki][ty * 4]);
      float4 b4 = *reinterpret_cast<const float4*>(&Bs[kki][tx * 4]);
      float a[4] = {a4.x, a4.y, a4.z, a4.w};
      float bv[4] = {b4.x, b4.y, b4.z, b4.w};
#pragma unroll
      for (int i = 0; i < 4; i++)
#pragma unroll
        for (int j = 0; j < 4; j++) acc[i][j] += a[i] * bv[j];
    }
  }
#pragma unroll
  for (int i = 0; i < 4; i++) {
    float* yr = yb + (size_t)(row0 + ty * 4 + i) * HW + col0 + tx * 4;
    *reinterpret_cast<float4*>(yr) = make_float4(acc[i][0], acc[i][1], acc[i][2], acc[i][3]);
  }
}

// ---------------- fused sample(64x64) + MaxPool2d_G -> 32x32, 1024 threads ---------
__global__ __launch_bounds__(1024, 4) void sampmax_kernel(
    const float* __restrict__ y, const float* __restrict__ geo,
    const float* __restrict__ box, float* __restrict__ out) {
  __shared__ __align__(16) float sp[64 * 68];      // sampled plane, padded stride
  __shared__ __align__(16) float arena[64 * 100];  // pl (ph1-2) then cb (ph3-4)
  __shared__ float wv[16];
  __shared__ int wi[16];
  __shared__ int am_s;
  float* pl = arena;
  float* cb = arena;

  int bc = blockIdx.x;
  int c = bc & (CC - 1);
  int b = bc >> 7;
  int tid = threadIdx.x;

  const float* plane = y + (size_t)bc * 4096;
  *reinterpret_cast<float4*>(&pl[tid * 4]) = *reinterpret_cast<const float4*>(&plane[tid * 4]);
  __syncthreads();

  {
    const float* g = geo + c * 6;
    const float* bx = box + c * 6;
    float g0 = g[0], g1 = g[1], g2 = g[2], g3 = g[3], g4 = g[4], g5 = g[5];
    float b0 = bx[0], b1 = bx[1], b2 = bx[2], b3 = bx[3], b4 = bx[4], b5 = bx[5];
#pragma unroll
    for (int k = 0; k < 4; ++k) {
      int px = tid + k * 1024;
      int h = px >> 6, w = px & 63;
      float xs = (2.0f * w + 1.0f) / 64.0f - 1.0f;
      float ys = (2.0f * h + 1.0f) / 64.0f - 1.0f;
      float gx = g0 * xs + g1 * ys + g2;
      float gy = g3 * xs + g4 * ys + g5;
      float ix = ((gx + 1.0f) * 64.0f - 1.0f) * 0.5f;
      float iy = ((gy + 1.0f) * 64.0f - 1.0f) * 0.5f;
      float x0 = floorf(ix), y0 = floorf(iy);
      float wx = ix - x0, wy = iy - y0;
      float v[2][2];
#pragma unroll
      for (int dy = 0; dy < 2; ++dy)
#pragma unroll
        for (int dx = 0; dx < 2; ++dx) {
          float xf = x0 + dx, yf = y0 + dy;
          bool valid = (xf >= 0.0f) && (xf <= 63.0f) && (yf >= 0.0f) && (yf <= 63.0f);
          int xi = (int)fminf(fmaxf(xf, 0.0f), 63.0f);
          int yi = (int)fminf(fmaxf(yf, 0.0f), 63.0f);
          v[dy][dx] = valid ? pl[yi * 64 + xi] : 0.0f;
        }
      float samp = (1.0f - wy) * ((1.0f - wx) * v[0][0] + wx * v[0][1]) +
                   wy * ((1.0f - wx) * v[1][0] + wx * v[1][1]);
      float bgx = b0 * xs + b1 * ys + b2;
      float bgy = b3 * xs + b4 * ys + b5;
      float bix = ((bgx + 1.0f) * 64.0f - 1.0f) * 0.5f;
      float biy = ((bgy + 1.0f) * 64.0f - 1.0f) * 0.5f;
      float bx0 = floorf(bix), by0 = floorf(biy);
      float bwx = bix - bx0, bwy = biy - by0;
      float m[2][2];
#pragma unroll
      for (int dy = 0; dy < 2; ++dy)
#pragma unroll
        for (int dx = 0; dx < 2; ++dx) {
          float xf = bx0 + dx, yf = by0 + dy;
          m[dy][dx] = ((xf >= 0.0f) && (xf <= 63.0f) && (yf >= 0.0f) && (yf <= 63.0f)) ? 1.0f : 0.0f;
        }
      float mask = (1.0f - bwy) * ((1.0f - bwx) * m[0][0] + bwx * m[0][1]) +
                   bwy * ((1.0f - bwx) * m[1][0] + bwx * m[1][1]);
      sp[h * 68 + w] = samp * mask;
    }
  }
  __syncthreads();

  if (tid < 256) {
    int strip = tid >> 4, w4 = (tid & 15) * 4;
    int h0 = strip * 4;
    float4 a0 = make_float4(0.f, 0.f, 0.f, 0.f), a1 = a0, a2 = a0, a3 = a0;
#pragma unroll
    for (int j = 0; j < 35; ++j) {
      int r = h0 + j - 16;
      bool valid = (r >= 0) && (r < 64);
      int rc = valid ? r : 0;
      float4 f = *reinterpret_cast<const float4*>(&sp[rc * 68 + w4]);
      f.x = valid ? f.x : 0.0f; f.y = valid ? f.y : 0.0f;
      f.z = valid ? f.z : 0.0f; f.w = valid ? f.w : 0.0f;
      if (j <= 31) { a0.x += f.x; a0.y += f.y; a0.z += f.z; a0.w += f.w; }
      if (j >= 1 && j <= 32) { a1.x += f.x; a1.y += f.y; a1.z += f.z; a1.w += f.w; }
      if (j >= 2 && j <= 33) { a2.x += f.x; a2.y += f.y; a2.z += f.z; a2.w += f.w; }
      if (j >= 3) { a3.x += f.x; a3.y += f.y; a3.z += f.z; a3.w += f.w; }
    }
    *reinterpret_cast<float4*>(&cb[(h0 + 0) * 100 + 16 + w4]) = a0;
    *reinterpret_cast<float4*>(&cb[(h0 + 1) * 100 + 16 + w4]) = a1;
    *reinterpret_cast<float4*>(&cb[(h0 + 2) * 100 + 16 + w4]) = a2;
    *reinterpret_cast<float4*>(&cb[(h0 + 3) * 100 + 16 + w4]) = a3;
  } else if (tid < 768) {
    int l = tid - 256;
    int row = l >> 3, gq = l & 7;
    int base = row * 100 + ((gq < 4) ? gq * 4 : 80 + (gq - 4) * 4);
    *reinterpret_cast<float4*>(&cb[base]) = make_float4(0.f, 0.f, 0.f, 0.f);
  }
  __syncthreads();

  float best = -3.402823466e+38f;
  int bidx = 0x7fffffff;
  {
    int h = tid >> 4, w4 = (tid & 15) * 4;
    float s0 = 0.f, s1 = 0.f, s2 = 0.f, s3 = 0.f;
#pragma unroll
    for (int q = 0; q < 9; ++q) {
      float4 f = *reinterpret_cast<const float4*>(&cb[h * 100 + w4 + 4 * q]);
      float fe[4] = {f.x, f.y, f.z, f.w};
#pragma unroll
      for (int e = 0; e < 4; ++e) {
        int u = 4 * q + e;
        if (u <= 31) s0 += fe[e];
        if (u >= 1 && u <= 32) s1 += fe[e];
        if (u >= 2 && u <= 33) s2 += fe[e];
        if (u >= 3 && u <= 34) s3 += fe[e];
      }
    }
    float sv[4] = {s0, s1, s2, s3};
#pragma unroll
    for (int d = 0; d < 4; ++d) {
      int i = (h << 6) + w4 + d;
      if (sv[d] > best) { best = sv[d]; bidx = i; }
    }
  }
#pragma unroll
  for (int off = 32; off > 0; off >>= 1) {
    float v2 = __shfl_down(best, off);
    int i2 = __shfl_down(bidx, off);
    if (v2 > best || (v2 == best && i2 < bidx)) { best = v2; bidx = i2; }
  }
  if ((tid & 63) == 0) { wv[tid >> 6] = best; wi[tid >> 6] = bidx; }
  __syncthreads();
  if (tid == 0) {
    float bv = wv[0]; int bi = wi[0];
#pragma unroll
    for (int k = 1; k < 16; ++k)
      if (wv[k] > bv || (wv[k] == bv && wi[k] < bi)) { bv = wv[k]; bi = wi[k]; }
    am_s = bi;
  }
  __syncthreads();

  int am = am_s;
  int r = am >> 6, cx = am & 63;
  float* o = out + (size_t)bc * 1024;
  {
    int oi = tid >> 5, oj = tid & 31;
    int rr = r + oi - 16, cj = cx + oj - 16;
    bool v = (rr >= 0) && (rr < 64) && (cj >= 0) && (cj < 64);
    int rrc = v ? rr : 0, cjc = v ? cj : 0;
    o[tid] = v ? sp[rrc * 68 + cjc] : 0.0f;
  }
}

// ---------------- fused 32x32 layer: GEMM (2 ch/block, grid 512) + sample + pool ----
// 2 blocks/CU (grid 512) doubles resident waves vs round-6's 1 block/CU.
template <bool POOL>
__global__ __launch_bounds__(256) void fused32_kernel(
    const float* __restrict__ lin, const float* __restrict__ x,
    const float* __restrict__ geo, const float* __restrict__ box,
    float* __restrict__ out, float* __restrict__ pooled) {
  const int H = 32, W = 32, HW = 1024;
  __shared__ __align__(16) float pls[2][1024];
  __shared__ float wred[8];
  int b = blockIdx.x & 7;                 // XCD swizzle: batch per XCD
  int c0 = (blockIdx.x >> 3) * 2;
  int tid = threadIdx.x;
  const float* xb = x + (size_t)b * 128 * HW;
  const float* l0 = lin + (c0 + 0) * 128;
  const float* l1 = lin + (c0 + 1) * 128;
  int px4 = tid * 4;

  float4 acc0 = make_float4(0.f, 0.f, 0.f, 0.f);
  float4 acc1 = acc0;
#pragma unroll 8
  for (int k = 0; k < 128; ++k) {
    float4 xv = *reinterpret_cast<const float4*>(&xb[(size_t)k * HW + px4]);
    float s0 = l0[k], s1 = l1[k];          // block-uniform -> s_load
    acc0.x += s0 * xv.x; acc0.y += s0 * xv.y; acc0.z += s0 * xv.z; acc0.w += s0 * xv.w;
    acc1.x += s1 * xv.x; acc1.y += s1 * xv.y; acc1.z += s1 * xv.z; acc1.w += s1 * xv.w;
  }
  *reinterpret_cast<float4*>(&pls[0][px4]) = acc0;
  *reinterpret_cast<float4*>(&pls[1][px4]) = acc1;
  __syncthreads();

  float psum[2] = {0.f, 0.f};
#pragma unroll
  for (int c = 0; c < 2; ++c) {
    const float* g = geo + (c0 + c) * 6;
    const float* bxp = box + (c0 + c) * 6;
    float g0 = g[0], g1 = g[1], g2 = g[2], g3 = g[3], g4 = g[4], g5 = g[5];
    float b0 = bxp[0], b1 = bxp[1], b2 = bxp[2], b3 = bxp[3], b4 = bxp[4], b5 = bxp[5];
    float* o = out + ((size_t)b * CC + c0 + c) * HW;
    const float* pl = pls[c];
#pragma unroll
    for (int k = 0; k < 4; ++k) {
      int px = tid + k * 256;
      int h = px >> 5, w = px & 31;
      float xs = (2.0f * w + 1.0f) / W - 1.0f;
      float ys = (2.0f * h + 1.0f) / H - 1.0f;
      float gx = g0 * xs + g1 * ys + g2;
      float gy = g3 * xs + g4 * ys + g5;
      float ix = ((gx + 1.0f) * W - 1.0f) * 0.5f;
      float iy = ((gy + 1.0f) * H - 1.0f) * 0.5f;
      float x0 = floorf(ix), y0 = floorf(iy);
      float wx = ix - x0, wy = iy - y0;
      float v[2][2];
#pragma unroll
      for (int dy = 0; dy < 2; ++dy)
#pragma unroll
        for (int dx = 0; dx < 2; ++dx) {
          float xf = x0 + dx, yf = y0 + dy;
          bool valid = (xf >= 0.0f) && (xf <= 31.0f) && (yf >= 0.0f) && (yf <= 31.0f);
          int xi = (int)fminf(fmaxf(xf, 0.0f), 31.0f);
          int yi = (int)fminf(fmaxf(yf, 0.0f), 31.0f);
          v[dy][dx] = valid ? pl[yi * 32 + xi] : 0.0f;
        }
      float samp = (1.0f - wy) * ((1.0f - wx) * v[0][0] + wx * v[0][1]) +
                   wy * ((1.0f - wx) * v[1][0] + wx * v[1][1]);
      float bgx = b0 * xs + b1 * ys + b2;
      float bgy = b3 * xs + b4 * ys + b5;
      float bix = ((bgx + 1.0f) * W - 1.0f) * 0.5f;
      float biy = ((bgy + 1.0f) * H - 1.0f) * 0.5f;
      float bx0 = floorf(bix), by0 = floorf(biy);
      float bwx = bix - bx0, bwy = biy - by0;
      float m[2][2];
#pragma unroll
      for (int dy = 0; dy < 2; ++dy)
#pragma unroll
        for (int dx = 0; dx < 2; ++dx) {
          float xf = bx0 + dx, yf = by0 + dy;
          m[dy][dx] = ((xf >= 0.0f) && (xf <= 31.0f) && (yf >= 0.0f) && (yf <= 31.0f)) ? 1.0f : 0.0f;
        }
      float mask = (1.0f - bwy) * ((1.0f - bwx) * m[0][0] + bwx * m[0][1]) +
                   bwy * ((1.0f - bwx) * m[1][0] + bwx * m[1][1]);
      float res = samp * mask;
      o[px] = res;
      if (POOL) psum[c] += res;
    }
  }
  if (POOL) {
    int lane = tid & 63, wid = tid >> 6;
#pragma unroll
    for (int c = 0; c < 2; ++c) {
      float r = psum[c];
#pragma unroll
      for (int off = 32; off > 0; off >>= 1) r += __shfl_down(r, off);
      if (lane == 0) wred[c * 4 + wid] = r;
    }
    __syncthreads();
    if (tid < 2) {
      float t = wred[tid * 4] + wred[tid * 4 + 1] + wred[tid * 4 + 2] + wred[tid * 4 + 3];
      pooled[b * CC + c0 + tid] = t * (1.0f / 1024.0f);
    }
  }
}

// ---------------- dense head ----------------
__global__ __launch_bounds__(128) void dense_kernel(
    const float* __restrict__ pooled, const float* __restrict__ w,
    const float* __restrict__ bias, float* __restrict__ out) {
  int t = threadIdx.x;
  if (t < 80) {
    int b = t / 10, o = t % 10;
    float s = bias[o];
    const float* pb = pooled + b * 128;
    const float* wo = w + o * 128;
    for (int c = 0; c < 128; ++c) s += pb[c] * wo[c];
    out[b * 10 + o] = s;
  }
}

extern "C" void kernel_launch(void* const* d_in, const int* in_sizes, int n_in,
                              void* d_out, int out_size, void* d_ws, size_t ws_size,
                              hipStream_t stream) {
  const float* x     = (const float*)d_in[0];   // [8,3,64,64]
  const float* geo0  = (const float*)d_in[1];   // [128,2,3]
  const float* lin0  = (const float*)d_in[2];   // [128,3]
  const float* box0  = (const float*)d_in[3];   // [128,2,3]
  const float* geos  = (const float*)d_in[4];   // [3,128,2,3]
  const float* lins  = (const float*)d_in[5];   // [3,128,128]
  const float* boxes = (const float*)d_in[6];   // [3,128,2,3]
  const float* dw    = (const float*)d_in[7];   // [10,128]
  const float* db    = (const float*)d_in[8];   // [10]

  float* out  = (float*)d_out;      // [8,10] then feat [8,128,32,32]
  float* feat = out + 80;
  float* ws   = (float*)d_ws;
  float* ws0  = ws;                 // 16 MB
  float* ws1  = ws + 4194304;       // 16 MB
  float* pooled = ws + 8388608;     // 1024 floats

  // inLay: fused combine(Ci=3) + sample -> ws1
  inlay_sample_kernel<<<dim3(BB * CC), 256, 0, stream>>>(x, lin0, geo0, box0, ws1);
  // layer 0: combine (64x64 tiles) -> fused sample+maxpool -> 32x32
  gemm64_kernel<<<dim3(64, 2, BB), 256, 0, stream>>>(lins, ws1, ws0, 4096);
  sampmax_kernel<<<dim3(BB * CC), 1024, 0, stream>>>(ws0, geos, boxes, ws1);
  // layer 2: fused GEMM + sample (2 ch/block, grid 512)
  fused32_kernel<false><<<dim3(512), 256, 0, stream>>>(lins + 16384, ws1, geos + 768, boxes + 768, ws0, nullptr);
  // layer 3: fused GEMM + sample + mean-pool, feat straight to d_out
  fused32_kernel<true><<<dim3(512), 256, 0, stream>>>(lins + 32768, ws0, geos + 1536, boxes + 1536, feat, pooled);
  // head
  dense_kernel<<<1, 128, 0, stream>>>(pooled, dw, db, out);
}